// Round 1
// baseline (926.976 us; speedup 1.0000x reference)
//
#include <hip/hip_runtime.h>
#include <math.h>

// MultiHeadAttention: B=2, S=2048, D=2048, H=16, dh=128, causal.
// fp16 MFMA pipeline: cast -> QKV gemms -> rope(inplace) -> V transpose ->
// flash attention -> output gemm (fp32 out).
// Workspace requirement: 96 MB (asserted by construction below).

typedef _Float16 half8 __attribute__((ext_vector_type(8)));
typedef _Float16 half4v __attribute__((ext_vector_type(4)));
typedef float f32x4 __attribute__((ext_vector_type(4)));

// ---------------- cast fp32 -> fp16 (4 elems / thread) ----------------
__global__ void cast_f32_f16(const float* __restrict__ src, _Float16* __restrict__ dst, int n4) {
  int i = blockIdx.x * blockDim.x + threadIdx.x;
  if (i >= n4) return;
  float4 v = reinterpret_cast<const float4*>(src)[i];
  half4v o;
  o[0] = (_Float16)v.x; o[1] = (_Float16)v.y; o[2] = (_Float16)v.z; o[3] = (_Float16)v.w;
  reinterpret_cast<half4v*>(dst)[i] = o;
}

// ---------------- GEMM: C[M,N] = A[M,K] * B[N,K]^T + bias ----------------
// 128x128 block tile, 4 waves, each wave 64x64 via 4x4 MFMA 16x16x32 f16.
template <bool OUT_F32>
__global__ __launch_bounds__(256) void gemm_bt(
    const _Float16* __restrict__ A,   // M x K
    const _Float16* __restrict__ B,   // N x K
    const float* __restrict__ bias,   // N
    void* __restrict__ Cout,          // M x N
    int M, int N, int K) {
  constexpr int BK = 32;
  __shared__ _Float16 As[128][BK + 8];  // +8 pad: 2-way bank aliasing (free)
  __shared__ _Float16 Bs[128][BK + 8];
  const int bm = blockIdx.y * 128, bn = blockIdx.x * 128;
  const int tid = threadIdx.x;
  const int wave = tid >> 6, lane = tid & 63;
  const int wm = (wave >> 1) * 64, wn = (wave & 1) * 64;
  const int quad = lane >> 4, l16 = lane & 15;

  f32x4 acc[4][4];
#pragma unroll
  for (int i = 0; i < 4; ++i)
#pragma unroll
    for (int n = 0; n < 4; ++n) acc[i][n] = f32x4{0.f, 0.f, 0.f, 0.f};

  for (int k0 = 0; k0 < K; k0 += BK) {
#pragma unroll
    for (int p = 0; p < 2; ++p) {
      int idx = p * 256 + tid;     // 512 chunks of 16B per tile
      int row = idx >> 2, seg = idx & 3;
      *reinterpret_cast<half8*>(&As[row][seg * 8]) =
          *reinterpret_cast<const half8*>(&A[(size_t)(bm + row) * K + k0 + seg * 8]);
      *reinterpret_cast<half8*>(&Bs[row][seg * 8]) =
          *reinterpret_cast<const half8*>(&B[(size_t)(bn + row) * K + k0 + seg * 8]);
    }
    __syncthreads();
    half8 af[4], bf[4];
#pragma unroll
    for (int i = 0; i < 4; ++i)
      af[i] = *reinterpret_cast<const half8*>(&As[wm + i * 16 + l16][quad * 8]);
#pragma unroll
    for (int n = 0; n < 4; ++n)
      bf[n] = *reinterpret_cast<const half8*>(&Bs[wn + n * 16 + l16][quad * 8]);
#pragma unroll
    for (int i = 0; i < 4; ++i)
#pragma unroll
      for (int n = 0; n < 4; ++n)
        acc[i][n] = __builtin_amdgcn_mfma_f32_16x16x32_f16(af[i], bf[n], acc[i][n], 0, 0, 0);
    __syncthreads();
  }

#pragma unroll
  for (int n = 0; n < 4; ++n) {
    const int gc = bn + wn + n * 16 + l16;
    const float bz = bias[gc];
#pragma unroll
    for (int i = 0; i < 4; ++i) {
#pragma unroll
      for (int r = 0; r < 4; ++r) {
        const int gr = bm + wm + i * 16 + quad * 4 + r;  // C/D: row=quad*4+reg, col=l16
        float v = acc[i][n][r] + bz;
        if (OUT_F32)
          reinterpret_cast<float*>(Cout)[(size_t)gr * N + gc] = v;
        else
          reinterpret_cast<_Float16*>(Cout)[(size_t)gr * N + gc] = (_Float16)v;
      }
    }
  }
}

// ---------------- RoPE in-place on (B,S,D) fp16, head-major cols ----------------
__global__ void rope_inplace(_Float16* __restrict__ q, _Float16* __restrict__ k, int npairs) {
  int idx = blockIdx.x * blockDim.x + threadIdx.x;
  if (idx >= npairs) return;
  int m = idx >> 10;       // row in (B*S), D/2 = 1024 pairs per row
  int pc = idx & 1023;     // pair col
  int i = pc & 63;         // freq index within head (dh/2=64)
  int s = m & 2047;        // sequence position
  float inv_freq = (float)pow(10000.0, -(double)i / 64.0);
  float ang = (float)s * inv_freq;
  float sn = sinf(ang), cs = cosf(ang);
  size_t a = (size_t)m * 2048 + pc * 2;
  float qe = (float)q[a], qo = (float)q[a + 1];
  q[a]     = (_Float16)(qe * cs - qo * sn);
  q[a + 1] = (_Float16)(qo * cs + qe * sn);
  float ke = (float)k[a], ko = (float)k[a + 1];
  k[a]     = (_Float16)(ke * cs - ko * sn);
  k[a + 1] = (_Float16)(ko * cs + ke * sn);
}

// ---------------- V transpose: (B,S,H,dh) -> (B,H,dh,S) ----------------
__global__ __launch_bounds__(256) void transpose_v(const _Float16* __restrict__ vlin,
                                                   _Float16* __restrict__ vt) {
  __shared__ _Float16 t[64][72];  // +8 pad
  const int s0 = blockIdx.x * 64;       // 32 tiles
  const int d0 = blockIdx.y * 64;       // 2 tiles
  const int bh = blockIdx.z;            // 32
  const int b = bh >> 4, h = bh & 15;
  const int tid = threadIdx.x;
#pragma unroll
  for (int p = 0; p < 2; ++p) {
    int chunk = p * 256 + tid;
    int r = chunk >> 3, c8 = (chunk & 7) * 8;
    *reinterpret_cast<half8*>(&t[r][c8]) = *reinterpret_cast<const half8*>(
        &vlin[(size_t)(b * 2048 + s0 + r) * 2048 + h * 128 + d0 + c8]);
  }
  __syncthreads();
#pragma unroll
  for (int p = 0; p < 2; ++p) {
    int chunk = p * 256 + tid;
    int dr = chunk >> 3, c8 = (chunk & 7) * 8;
    half8 o;
#pragma unroll
    for (int j = 0; j < 8; ++j) o[j] = t[c8 + j][dr];
    *reinterpret_cast<half8*>(&vt[(size_t)(bh * 128 + d0 + dr) * 2048 + s0 + c8]) = o;
  }
}

// ---------------- Flash attention (causal) ----------------
// Q,K: (B,S,D) roped fp16; VT: (B,H,dh,S) fp16; ctx out: (B,S,D) fp16.
// Block = (q tile of 64 rows) x (one b,h). 4 waves, each owns 16 Q-rows
// independently (no barriers -> waves may run different key-trip counts).
__global__ __launch_bounds__(256) void attn_kernel(
    const _Float16* __restrict__ Q, const _Float16* __restrict__ Km,
    const _Float16* __restrict__ VT, _Float16* __restrict__ ctx) {
  constexpr int S = 2048, D = 2048, DH = 128;
  __shared__ _Float16 P[4][16][40];  // per-wave P tile (16 rows x 32 keys, +8 pad)
  const int qt = blockIdx.x, bh = blockIdx.y;
  const int b = bh >> 4, h = bh & 15;
  const int wave = threadIdx.x >> 6, lane = threadIdx.x & 63;
  const int quad = lane >> 4, l16 = lane & 15;
  const int q0 = qt * 64 + wave * 16;

  // Q fragments for this wave's 16 rows, all 4 K=32 steps (kept in regs)
  const _Float16* qp = Q + (size_t)(b * S + q0 + l16) * D + h * DH;
  half8 aq[4];
#pragma unroll
  for (int s = 0; s < 4; ++s) aq[s] = *reinterpret_cast<const half8*>(qp + s * 32 + quad * 8);

  f32x4 acc[8];
#pragma unroll
  for (int t = 0; t < 8; ++t) acc[t] = f32x4{0.f, 0.f, 0.f, 0.f};
  float m_i[4], l_i[4];
#pragma unroll
  for (int r = 0; r < 4; ++r) { m_i[r] = -INFINITY; l_i[r] = 0.f; }

  const float scale = 0.088388347648318447f;  // 1/sqrt(128)
  const int nkt = (q0 + 16 + 31) >> 5;        // 32-key tiles covering keys <= q0+15

  for (int kt = 0; kt < nkt; ++kt) {
    const int key0 = kt * 32;
    // ---- scores: 16 q-rows x 32 keys ----
    f32x4 sf[2];
#pragma unroll
    for (int f = 0; f < 2; ++f) {
      f32x4 s4 = f32x4{0.f, 0.f, 0.f, 0.f};
      const _Float16* kp = Km + (size_t)(b * S + key0 + f * 16 + l16) * D + h * DH;
#pragma unroll
      for (int ks = 0; ks < 4; ++ks) {
        half8 bk = *reinterpret_cast<const half8*>(kp + ks * 32 + quad * 8);
        s4 = __builtin_amdgcn_mfma_f32_16x16x32_f16(aq[ks], bk, s4, 0, 0, 0);
      }
      sf[f] = s4;
    }
    // ---- scale + causal mask (score layout: row=quad*4+r, col=l16) ----
#pragma unroll
    for (int f = 0; f < 2; ++f) {
      const int key = key0 + f * 16 + l16;
#pragma unroll
      for (int r = 0; r < 4; ++r) {
        const int qrow = q0 + quad * 4 + r;
        float sv = sf[f][r] * scale;
        sf[f][r] = (key <= qrow) ? sv : -1e30f;
      }
    }
    // ---- online softmax ----
    float alpha[4];
#pragma unroll
    for (int r = 0; r < 4; ++r) {
      float tm = fmaxf(sf[0][r], sf[1][r]);
      tm = fmaxf(tm, __shfl_xor(tm, 1));
      tm = fmaxf(tm, __shfl_xor(tm, 2));
      tm = fmaxf(tm, __shfl_xor(tm, 4));
      tm = fmaxf(tm, __shfl_xor(tm, 8));
      float mn = fmaxf(m_i[r], tm);
      alpha[r] = __expf(m_i[r] - mn);  // exp(-inf)=0 on first tile
      m_i[r] = mn;
      float p0 = __expf(sf[0][r] - mn);
      float p1 = __expf(sf[1][r] - mn);
      sf[0][r] = p0; sf[1][r] = p1;
      float ts = p0 + p1;
      ts += __shfl_xor(ts, 1);
      ts += __shfl_xor(ts, 2);
      ts += __shfl_xor(ts, 4);
      ts += __shfl_xor(ts, 8);
      l_i[r] = l_i[r] * alpha[r] + ts;
    }
    // ---- P: C-layout -> LDS -> A-layout (m120-verified round trip) ----
#pragma unroll
    for (int f = 0; f < 2; ++f)
#pragma unroll
      for (int r = 0; r < 4; ++r)
        P[wave][quad * 4 + r][f * 16 + l16] = (_Float16)sf[f][r];
    half8 pa = *reinterpret_cast<const half8*>(&P[wave][l16][quad * 8]);
    // ---- PV: O += P (16x32) * V (32 keys x 128 dh) ----
#pragma unroll
    for (int t = 0; t < 8; ++t) {
      const _Float16* vp = VT + (size_t)(bh * DH + t * 16 + l16) * S + key0 + quad * 8;
      half8 bv = *reinterpret_cast<const half8*>(vp);
      f32x4 c = acc[t];
#pragma unroll
      for (int r = 0; r < 4; ++r) c[r] *= alpha[r];
      acc[t] = __builtin_amdgcn_mfma_f32_16x16x32_f16(pa, bv, c, 0, 0, 0);
    }
  }
  // ---- epilogue: normalize, write ctx (B,S,D) ----
#pragma unroll
  for (int t = 0; t < 8; ++t)
#pragma unroll
    for (int r = 0; r < 4; ++r)
      ctx[(size_t)(b * S + q0 + quad * 4 + r) * D + h * DH + t * 16 + l16] =
          (_Float16)(acc[t][r] / l_i[r]);
}

// ---------------- launcher ----------------
extern "C" void kernel_launch(void* const* d_in, const int* in_sizes, int n_in,
                              void* d_out, int out_size, void* d_ws, size_t ws_size,
                              hipStream_t stream) {
  const float* x  = (const float*)d_in[0];
  const float* wq = (const float*)d_in[1];
  const float* bq = (const float*)d_in[2];
  const float* wk = (const float*)d_in[3];
  const float* bk = (const float*)d_in[4];
  const float* wv = (const float*)d_in[5];
  const float* bv = (const float*)d_in[6];
  const float* wo = (const float*)d_in[7];
  const float* bo = (const float*)d_in[8];
  // d_in[9] = mask: causal triu(k=1), hardcoded in attn_kernel.

  // workspace layout (fp16 elements); total 96 MB
  _Float16* W    = (_Float16*)d_ws;
  _Float16* xh   = W;                 // 8388608  (B,S,D)
  _Float16* wqh  = xh + 8388608;      // 4194304
  _Float16* wkh  = wqh + 4194304;     // 4194304
  _Float16* wvh  = wkh + 4194304;     // 4194304
  _Float16* woh  = wvh + 4194304;     // 4194304
  _Float16* qlin = woh + 4194304;     // 8388608  (B,S,D)
  _Float16* klin = qlin + 8388608;    // 8388608
  _Float16* vlin = klin + 8388608;    // 8388608
  _Float16* vT   = xh;                // reuse: x dead after QKV gemms
  _Float16* ctx  = wqh;               // reuse: wq/wk dead after their gemms

  cast_f32_f16<<<8192, 256, 0, stream>>>(x, xh, 2097152);
  cast_f32_f16<<<4096, 256, 0, stream>>>(wq, wqh, 1048576);
  cast_f32_f16<<<4096, 256, 0, stream>>>(wk, wkh, 1048576);
  cast_f32_f16<<<4096, 256, 0, stream>>>(wv, wvh, 1048576);
  cast_f32_f16<<<4096, 256, 0, stream>>>(wo, woh, 1048576);

  dim3 gg(16, 32);  // N/128, M/128
  gemm_bt<false><<<gg, 256, 0, stream>>>(xh, wqh, bq, qlin, 4096, 2048, 2048);
  gemm_bt<false><<<gg, 256, 0, stream>>>(xh, wkh, bk, klin, 4096, 2048, 2048);
  gemm_bt<false><<<gg, 256, 0, stream>>>(xh, wvh, bv, vlin, 4096, 2048, 2048);

  rope_inplace<<<16384, 256, 0, stream>>>(qlin, klin, 4194304);
  transpose_v<<<dim3(32, 2, 32), 256, 0, stream>>>(vlin, vT);
  attn_kernel<<<dim3(32, 32), 256, 0, stream>>>(qlin, klin, vT, ctx);

  gemm_bt<true><<<gg, 256, 0, stream>>>(ctx, woh, bo, (float*)d_out, 4096, 2048, 2048);
}

// Round 2
// 611.264 us; speedup vs baseline: 1.5165x; 1.5165x over previous
//
#include <hip/hip_runtime.h>
#include <math.h>

// MultiHeadAttention: B=2, S=2048, D=2048, H=16, dh=128, causal.
// fp16 MFMA pipeline: cast -> QKV gemms (m97-style global_load_lds) ->
// rope(inplace) -> V transpose -> LDS-staged flash attention -> output gemm.

typedef _Float16 half8 __attribute__((ext_vector_type(8)));
typedef _Float16 half4v __attribute__((ext_vector_type(4)));
typedef float f32x4 __attribute__((ext_vector_type(4)));

// async 16B global -> LDS (lands at wave-uniform base + lane*16)
__device__ __forceinline__ void gl_lds16(const void* g, void* l) {
  __builtin_amdgcn_global_load_lds(
      (const __attribute__((address_space(1))) unsigned int*)g,
      (__attribute__((address_space(3))) unsigned int*)l, 16, 0, 0);
}

// ---------------- cast fp32 -> fp16 (4 elems / thread) ----------------
__global__ void cast_f32_f16(const float* __restrict__ src, _Float16* __restrict__ dst, int n4) {
  int i = blockIdx.x * blockDim.x + threadIdx.x;
  if (i >= n4) return;
  float4 v = reinterpret_cast<const float4*>(src)[i];
  half4v o;
  o[0] = (_Float16)v.x; o[1] = (_Float16)v.y; o[2] = (_Float16)v.z; o[3] = (_Float16)v.w;
  reinterpret_cast<half4v*>(dst)[i] = o;
}

// ---------------- GEMM: C[M,N] = A[M,K] * B[N,K]^T + bias ----------------
// 128x128 block tile, 4 waves (2x2 of 64x64), BK=32.
// LDS is fragment-major: chunk index ((half*4 + i)*4 + quad)*16 + l16, 16B each.
// Staged with global_load_lds width 16; all ds_read_b128 conflict-free.
template <bool OUT_F32>
__global__ __launch_bounds__(256, 2) void gemm_bt(
    const _Float16* __restrict__ A,   // M x K
    const _Float16* __restrict__ B,   // N x K
    const float* __restrict__ bias,   // N
    void* __restrict__ Cout,          // M x N
    int M, int N, int K) {
  __shared__ _Float16 As[4096];  // 8 KB
  __shared__ _Float16 Bs[4096];  // 8 KB
  const int bm = blockIdx.y * 128, bn = blockIdx.x * 128;
  const int tid = threadIdx.x;
  const int wave = tid >> 6, lane = tid & 63;
  const int quad = lane >> 4, l16 = lane & 15;
  const int hh = wave >> 1, gg = wave & 1;  // wave's 64-row halves of A / B

  // staging decode: p=0,1 -> A chunks [0,512); p=2,3 -> B chunks [0,512)
  const _Float16* gsrc[4];
  _Float16* ldst[4];
#pragma unroll
  for (int p = 0; p < 4; ++p) {
    int c = ((p & 1) * 256 + tid) & 511;           // chunk in [0,512)
    int cl16 = c & 15, cqd = (c >> 4) & 3, ci = (c >> 6) & 3, ch = c >> 8;
    int grow = ch * 64 + ci * 16 + cl16;           // row within 128-tile
    int gcol = cqd * 8;                            // f16 col within BK=32
    if (p < 2) {
      gsrc[p] = A + (size_t)(bm + grow) * K + gcol;
      ldst[p] = As + (size_t)c * 8;
    } else {
      gsrc[p] = B + (size_t)(bn + grow) * K + gcol;
      ldst[p] = Bs + (size_t)c * 8;
    }
  }

  f32x4 acc[4][4];
#pragma unroll
  for (int i = 0; i < 4; ++i)
#pragma unroll
    for (int n = 0; n < 4; ++n) acc[i][n] = f32x4{0.f, 0.f, 0.f, 0.f};

  for (int k0 = 0; k0 < K; k0 += 32) {
    __syncthreads();  // previous iter's LDS reads done
#pragma unroll
    for (int p = 0; p < 4; ++p) gl_lds16(gsrc[p] + k0, ldst[p]);
    __syncthreads();  // staged data visible (vmcnt(0) drained at barrier)

    half8 af[4], bf[4];
#pragma unroll
    for (int i = 0; i < 4; ++i)
      af[i] = *reinterpret_cast<const half8*>(As + ((hh * 4 + i) * 4 + quad) * 128 + l16 * 8);
#pragma unroll
    for (int n = 0; n < 4; ++n)
      bf[n] = *reinterpret_cast<const half8*>(Bs + ((gg * 4 + n) * 4 + quad) * 128 + l16 * 8);
#pragma unroll
    for (int i = 0; i < 4; ++i)
#pragma unroll
      for (int n = 0; n < 4; ++n)
        acc[i][n] = __builtin_amdgcn_mfma_f32_16x16x32_f16(af[i], bf[n], acc[i][n], 0, 0, 0);
  }

  const int wm = hh * 64, wn = gg * 64;
#pragma unroll
  for (int n = 0; n < 4; ++n) {
    const int gc = bn + wn + n * 16 + l16;
    const float bz = bias[gc];
#pragma unroll
    for (int i = 0; i < 4; ++i) {
#pragma unroll
      for (int r = 0; r < 4; ++r) {
        const int gr = bm + wm + i * 16 + quad * 4 + r;  // C/D: row=quad*4+reg, col=l16
        float v = acc[i][n][r] + bz;
        if (OUT_F32)
          reinterpret_cast<float*>(Cout)[(size_t)gr * N + gc] = v;
        else
          reinterpret_cast<_Float16*>(Cout)[(size_t)gr * N + gc] = (_Float16)v;
      }
    }
  }
}

// ---------------- RoPE in-place, 4 pairs (16B) per thread ----------------
__global__ void rope_inplace(_Float16* __restrict__ q, _Float16* __restrict__ k, int ngroups) {
  int idx = blockIdx.x * blockDim.x + threadIdx.x;
  if (idx >= ngroups) return;
  int m = idx >> 8;        // row in (B*S); 256 groups of 4 pairs per row (D/2=1024)
  int g = idx & 255;       // group of 4 consecutive pairs
  int s = m & 2047;        // sequence position
  size_t base = (size_t)m * 2048 + g * 8;
  half8 qv = *reinterpret_cast<const half8*>(q + base);
  half8 kv = *reinterpret_cast<const half8*>(k + base);
  half8 qo, ko;
#pragma unroll
  for (int j = 0; j < 4; ++j) {
    int i = (g * 4 + j) & 63;  // freq index within head (dh/2 = 64)
    // 10000^(-i/64) = 2^(-i * log2(10000)/64)
    float ang = (float)s * exp2f(-0.2076205059304601f * (float)i);
    float sn = sinf(ang), cs = cosf(ang);
    float e = (float)qv[j * 2], o = (float)qv[j * 2 + 1];
    qo[j * 2]     = (_Float16)(e * cs - o * sn);
    qo[j * 2 + 1] = (_Float16)(o * cs + e * sn);
    e = (float)kv[j * 2]; o = (float)kv[j * 2 + 1];
    ko[j * 2]     = (_Float16)(e * cs - o * sn);
    ko[j * 2 + 1] = (_Float16)(o * cs + e * sn);
  }
  *reinterpret_cast<half8*>(q + base) = qo;
  *reinterpret_cast<half8*>(k + base) = ko;
}

// ---------------- V transpose: (B,S,H,dh) -> (B,H,dh,S) ----------------
__global__ __launch_bounds__(256) void transpose_v(const _Float16* __restrict__ vlin,
                                                   _Float16* __restrict__ vt) {
  __shared__ _Float16 t[64][72];
  const int s0 = blockIdx.x * 64;
  const int d0 = blockIdx.y * 64;
  const int bh = blockIdx.z;
  const int b = bh >> 4, h = bh & 15;
  const int tid = threadIdx.x;
#pragma unroll
  for (int p = 0; p < 2; ++p) {
    int chunk = p * 256 + tid;
    int r = chunk >> 3, c8 = (chunk & 7) * 8;
    *reinterpret_cast<half8*>(&t[r][c8]) = *reinterpret_cast<const half8*>(
        &vlin[(size_t)(b * 2048 + s0 + r) * 2048 + h * 128 + d0 + c8]);
  }
  __syncthreads();
#pragma unroll
  for (int p = 0; p < 2; ++p) {
    int chunk = p * 256 + tid;
    int dr = chunk >> 3, c8 = (chunk & 7) * 8;
    half8 o;
#pragma unroll
    for (int j = 0; j < 8; ++j) o[j] = t[c8 + j][dr];
    *reinterpret_cast<half8*>(&vt[(size_t)(bh * 128 + d0 + dr) * 2048 + s0 + c8]) = o;
  }
}

// ---------------- Flash attention (causal), LDS-staged K/V ----------------
// Block: 128 Q rows x one (b,h); 4 waves x 32 rows. Key tiles of 64,
// K (64x128) and V^T (128x64) staged fragment-major via global_load_lds,
// shared by all waves. P round-trips through padded LDS (C->A layout).
__global__ __launch_bounds__(256, 2) void attn_kernel(
    const _Float16* __restrict__ Q, const _Float16* __restrict__ Km,
    const _Float16* __restrict__ VT, _Float16* __restrict__ ctx) {
  constexpr int S = 2048, D = 2048;
  __shared__ _Float16 Ks[8192];      // 16 KB, fragment chunks ((f*4+ks)*4+quad)*16+l16
  __shared__ _Float16 Vs[8192];      // 16 KB, fragment chunks ((t*2+kv)*4+quad)*16+l16
  __shared__ _Float16 P[4][32][72];  // 18 KB, per-wave P (stride 144 B = 16B-aligned)
  const int qt = blockIdx.x, bh = blockIdx.y;
  const int b = bh >> 4, h = bh & 15;
  const int tid = threadIdx.x;
  const int wv = tid >> 6, lane = tid & 63;
  const int quad = lane >> 4, l16 = lane & 15;
  const int q0 = qt * 128 + wv * 32;  // wave's first Q row

  // Q fragments: 2 row-tiles x 4 k-steps, kept in regs for the whole kernel
  half8 aq[2][4];
#pragma unroll
  for (int rt = 0; rt < 2; ++rt)
#pragma unroll
    for (int ks = 0; ks < 4; ++ks)
      aq[rt][ks] = *reinterpret_cast<const half8*>(
          Q + (size_t)(b * S + q0 + rt * 16 + l16) * D + h * 128 + ks * 32 + quad * 8);

  // staging addresses: p=0..3 K chunks, p=4..7 V chunks (1024 each)
  const _Float16* gk[4];
  const _Float16* gv[4];
  _Float16 *lk[4], *lv[4];
#pragma unroll
  for (int p = 0; p < 4; ++p) {
    int c = p * 256 + tid;  // [0,1024)
    int cl16 = c & 15, cqd = (c >> 4) & 3;
    int cks = (c >> 6) & 3, cf = c >> 8;
    gk[p] = Km + (size_t)(b * S + cf * 16 + cl16) * D + h * 128 + cks * 32 + cqd * 8;
    lk[p] = Ks + (size_t)c * 8;
    int ckv = (c >> 6) & 1, ct = c >> 7;
    gv[p] = VT + (size_t)(bh * 128 + ct * 16 + cl16) * S + ckv * 32 + cqd * 8;
    lv[p] = Vs + (size_t)c * 8;
  }

  f32x4 acc[2][8];
#pragma unroll
  for (int rt = 0; rt < 2; ++rt)
#pragma unroll
    for (int t = 0; t < 8; ++t) acc[rt][t] = f32x4{0.f, 0.f, 0.f, 0.f};
  float m_i[2][4], l_i[2][4];
#pragma unroll
  for (int rt = 0; rt < 2; ++rt)
#pragma unroll
    for (int r = 0; r < 4; ++r) { m_i[rt][r] = -INFINITY; l_i[rt][r] = 0.f; }

  const float scale = 0.088388347648318447f;  // 1/sqrt(128)
  const int nkt = 2 * (qt + 1);               // 64-key tiles covering keys <= qt*128+127

  for (int kt = 0; kt < nkt; ++kt) {
    const int key0 = kt * 64;
    __syncthreads();  // prior tile's LDS reads complete before overwrite
    const size_t kofs = (size_t)key0 * D;
#pragma unroll
    for (int p = 0; p < 4; ++p) gl_lds16(gk[p] + kofs, lk[p]);
#pragma unroll
    for (int p = 0; p < 4; ++p) gl_lds16(gv[p] + key0, lv[p]);
    __syncthreads();  // staged (vmcnt(0) drains at barrier)

    if (key0 <= q0) {  // wave has at least one unmasked key in this tile
      // ---- QK^T: 32 rows x 64 keys ----
      f32x4 sf[2][4];
#pragma unroll
      for (int rt = 0; rt < 2; ++rt)
#pragma unroll
        for (int f = 0; f < 4; ++f) sf[rt][f] = f32x4{0.f, 0.f, 0.f, 0.f};
#pragma unroll
      for (int f = 0; f < 4; ++f)
#pragma unroll
        for (int ks = 0; ks < 4; ++ks) {
          half8 bk = *reinterpret_cast<const half8*>(Ks + ((f * 4 + ks) * 4 + quad) * 128 + l16 * 8);
          sf[0][f] = __builtin_amdgcn_mfma_f32_16x16x32_f16(aq[0][ks], bk, sf[0][f], 0, 0, 0);
          sf[1][f] = __builtin_amdgcn_mfma_f32_16x16x32_f16(aq[1][ks], bk, sf[1][f], 0, 0, 0);
        }
      // ---- scale + causal mask + online softmax + P write ----
      float alpha[2][4];
#pragma unroll
      for (int rt = 0; rt < 2; ++rt) {
#pragma unroll
        for (int f = 0; f < 4; ++f) {
          const int key = key0 + f * 16 + l16;
#pragma unroll
          for (int r = 0; r < 4; ++r) {
            const int row = q0 + rt * 16 + quad * 4 + r;
            float sv = sf[rt][f][r] * scale;
            sf[rt][f][r] = (key <= row) ? sv : -1e30f;
          }
        }
#pragma unroll
        for (int r = 0; r < 4; ++r) {
          float tm = fmaxf(fmaxf(sf[rt][0][r], sf[rt][1][r]), fmaxf(sf[rt][2][r], sf[rt][3][r]));
          tm = fmaxf(tm, __shfl_xor(tm, 1));
          tm = fmaxf(tm, __shfl_xor(tm, 2));
          tm = fmaxf(tm, __shfl_xor(tm, 4));
          tm = fmaxf(tm, __shfl_xor(tm, 8));
          const float mn = fmaxf(m_i[rt][r], tm);
          const float al = __expf(m_i[rt][r] - mn);
          m_i[rt][r] = mn;
          alpha[rt][r] = al;
          float ts = 0.f;
#pragma unroll
          for (int f = 0; f < 4; ++f) {
            const float pv = __expf(sf[rt][f][r] - mn);
            sf[rt][f][r] = pv;
            ts += pv;
          }
          ts += __shfl_xor(ts, 1);
          ts += __shfl_xor(ts, 2);
          ts += __shfl_xor(ts, 4);
          ts += __shfl_xor(ts, 8);
          l_i[rt][r] = l_i[rt][r] * al + ts;
        }
#pragma unroll
        for (int f = 0; f < 4; ++f)
#pragma unroll
          for (int r = 0; r < 4; ++r)
            P[wv][rt * 16 + quad * 4 + r][f * 16 + l16] = (_Float16)sf[rt][f][r];
      }
      // ---- P: C-layout -> A-layout via LDS ----
      half8 pa[2][2];
#pragma unroll
      for (int rt = 0; rt < 2; ++rt)
#pragma unroll
        for (int kv = 0; kv < 2; ++kv)
          pa[rt][kv] = *reinterpret_cast<const half8*>(&P[wv][rt * 16 + l16][kv * 32 + quad * 8]);
      // ---- PV: O = diag(alpha)*O + P*V ----
#pragma unroll
      for (int rt = 0; rt < 2; ++rt)
#pragma unroll
        for (int t = 0; t < 8; ++t) {
          f32x4 c = acc[rt][t];
#pragma unroll
          for (int r = 0; r < 4; ++r) c[r] *= alpha[rt][r];
#pragma unroll
          for (int kv = 0; kv < 2; ++kv) {
            half8 bv = *reinterpret_cast<const half8*>(Vs + ((t * 2 + kv) * 4 + quad) * 128 + l16 * 8);
            c = __builtin_amdgcn_mfma_f32_16x16x32_f16(pa[rt][kv], bv, c, 0, 0, 0);
          }
          acc[rt][t] = c;
        }
    }
  }

  // ---- epilogue: normalize, write ctx (B,S,D) ----
#pragma unroll
  for (int rt = 0; rt < 2; ++rt)
#pragma unroll
    for (int t = 0; t < 8; ++t)
#pragma unroll
      for (int r = 0; r < 4; ++r)
        ctx[(size_t)(b * S + q0 + rt * 16 + quad * 4 + r) * D + h * 128 + t * 16 + l16] =
            (_Float16)(acc[rt][t][r] / l_i[rt][r]);
}

// ---------------- launcher ----------------
extern "C" void kernel_launch(void* const* d_in, const int* in_sizes, int n_in,
                              void* d_out, int out_size, void* d_ws, size_t ws_size,
                              hipStream_t stream) {
  const float* x  = (const float*)d_in[0];
  const float* wq = (const float*)d_in[1];
  const float* bq = (const float*)d_in[2];
  const float* wk = (const float*)d_in[3];
  const float* bk = (const float*)d_in[4];
  const float* wv = (const float*)d_in[5];
  const float* bv = (const float*)d_in[6];
  const float* wo = (const float*)d_in[7];
  const float* bo = (const float*)d_in[8];
  // d_in[9] = mask: causal triu(k=1), hardcoded in attn_kernel.

  _Float16* W    = (_Float16*)d_ws;
  _Float16* xh   = W;                 // 16 MB (B,S,D)
  _Float16* wqh  = xh + 8388608;      // 8 MB
  _Float16* wkh  = wqh + 4194304;     // 8 MB
  _Float16* wvh  = wkh + 4194304;     // 8 MB
  _Float16* woh  = wvh + 4194304;     // 8 MB
  _Float16* qlin = woh + 4194304;     // 16 MB
  _Float16* klin = qlin + 8388608;    // 16 MB
  _Float16* vlin = klin + 8388608;    // 16 MB
  _Float16* vT   = xh;                // reuse: x dead after QKV gemms
  _Float16* ctx  = wqh;               // reuse: wq/wk dead after their gemms

  cast_f32_f16<<<8192, 256, 0, stream>>>(x, xh, 2097152);
  cast_f32_f16<<<4096, 256, 0, stream>>>(wq, wqh, 1048576);
  cast_f32_f16<<<4096, 256, 0, stream>>>(wk, wkh, 1048576);
  cast_f32_f16<<<4096, 256, 0, stream>>>(wv, wvh, 1048576);
  cast_f32_f16<<<4096, 256, 0, stream>>>(wo, woh, 1048576);

  dim3 gg(16, 32);  // N/128, M/128
  gemm_bt<false><<<gg, 256, 0, stream>>>(xh, wqh, bq, qlin, 4096, 2048, 2048);
  gemm_bt<false><<<gg, 256, 0, stream>>>(xh, wkh, bk, klin, 4096, 2048, 2048);
  gemm_bt<false><<<gg, 256, 0, stream>>>(xh, wvh, bv, vlin, 4096, 2048, 2048);

  rope_inplace<<<4096, 256, 0, stream>>>(qlin, klin, 1048576);
  transpose_v<<<dim3(32, 2, 32), 256, 0, stream>>>(vlin, vT);
  attn_kernel<<<dim3(16, 32), 256, 0, stream>>>(qlin, klin, vT, ctx);

  gemm_bt<true><<<gg, 256, 0, stream>>>(ctx, woh, bo, (float*)d_out, 4096, 2048, 2048);
}

// Round 3
// 518.922 us; speedup vs baseline: 1.7863x; 1.1780x over previous
//
#include <hip/hip_runtime.h>
#include <math.h>

// MultiHeadAttention: B=2, S=2048, D=2048, H=16, dh=128, causal.
// v3: fused QKV gemm (N=6144, 1536 blocks), dbuf single-barrier K-loops,
// dbuf'd heavy-first flash attention with MFMA row-sums.

typedef _Float16 half8 __attribute__((ext_vector_type(8)));
typedef _Float16 half4v __attribute__((ext_vector_type(4)));
typedef float f32x4 __attribute__((ext_vector_type(4)));

__device__ __forceinline__ void gl_lds16(const void* g, void* l) {
  __builtin_amdgcn_global_load_lds(
      (const __attribute__((address_space(1))) unsigned int*)g,
      (__attribute__((address_space(3))) unsigned int*)l, 16, 0, 0);
}

// ---------------- cast fp32 -> fp16 ----------------
__global__ void cast_f32_f16(const float* __restrict__ src, _Float16* __restrict__ dst, int n4) {
  int i = blockIdx.x * blockDim.x + threadIdx.x;
  if (i >= n4) return;
  float4 v = reinterpret_cast<const float4*>(src)[i];
  half4v o;
  o[0] = (_Float16)v.x; o[1] = (_Float16)v.y; o[2] = (_Float16)v.z; o[3] = (_Float16)v.w;
  reinterpret_cast<half4v*>(dst)[i] = o;
}

// all 4 weights (each 4M f32) in one dispatch; dsts contiguous at wdst
__global__ void cast_w(const float* __restrict__ w0, const float* __restrict__ w1,
                       const float* __restrict__ w2, const float* __restrict__ w3,
                       _Float16* __restrict__ wdst) {
  const float* s = blockIdx.y == 0 ? w0 : blockIdx.y == 1 ? w1 : blockIdx.y == 2 ? w2 : w3;
  int i = blockIdx.x * blockDim.x + threadIdx.x;  // < 1048576 float4 groups
  float4 v = reinterpret_cast<const float4*>(s)[i];
  half4v o;
  o[0] = (_Float16)v.x; o[1] = (_Float16)v.y; o[2] = (_Float16)v.z; o[3] = (_Float16)v.w;
  reinterpret_cast<half4v*>(wdst)[(size_t)blockIdx.y * 1048576 + i] = o;
}

// ---------------- GEMM: C[M,N] = A[M,K] * B[N,K]^T + bias ----------------
// 128x128 tile, 4 waves (2x2 of 64x64), BK=32, double-buffered LDS with a
// single barrier per K-step: barrier -> issue next-tile global_load_lds ->
// compute current (loads fly during MFMA) -> barrier drains at loop top.
template <bool OUT_F32>
__global__ __launch_bounds__(256, 2) void gemm_bt(
    const _Float16* __restrict__ A,   // M x K
    const _Float16* __restrict__ B,   // N x K
    const float* __restrict__ b0, const float* __restrict__ b1,
    const float* __restrict__ b2,     // bias for col/2048 == 0,1,2
    void* __restrict__ Cout,          // M x N
    int M, int N, int K) {
  __shared__ _Float16 As[2][4096];  // 16 KB
  __shared__ _Float16 Bs[2][4096];  // 16 KB
  const int bm = blockIdx.y * 128, bn = blockIdx.x * 128;
  const int tid = threadIdx.x;
  const int wave = tid >> 6, lane = tid & 63;
  const int quad = lane >> 4, l16 = lane & 15;
  const int hh = wave >> 1, gg = wave & 1;

  // staging decode: p=0,1 -> A chunks, p=2,3 -> B chunks (512 x 16B each)
  const _Float16* gsrc[4];
  int lofs[4];
#pragma unroll
  for (int p = 0; p < 4; ++p) {
    int c = ((p & 1) * 256 + tid) & 511;
    int cl16 = c & 15, cqd = (c >> 4) & 3, ci = (c >> 6) & 3, ch = c >> 8;
    int grow = ch * 64 + ci * 16 + cl16;
    int gcol = cqd * 8;
    gsrc[p] = (p < 2 ? A + (size_t)(bm + grow) * K : B + (size_t)(bn + grow) * K) + gcol;
    lofs[p] = c * 8;
  }

  f32x4 acc[4][4];
#pragma unroll
  for (int i = 0; i < 4; ++i)
#pragma unroll
    for (int n = 0; n < 4; ++n) acc[i][n] = f32x4{0.f, 0.f, 0.f, 0.f};

  // prologue: stage k-step 0 into buf 0
#pragma unroll
  for (int p = 0; p < 4; ++p)
    gl_lds16(gsrc[p], (p < 2 ? &As[0][lofs[p]] : &Bs[0][lofs[p]]));

  const int nit = K >> 5;
  for (int it = 0; it < nit; ++it) {
    __syncthreads();  // drains vmcnt: buf[it&1] staged; prior reads done
    const int cur = it & 1;
    if (it + 1 < nit) {
      const int nxt = cur ^ 1, ko = (it + 1) * 32;
#pragma unroll
      for (int p = 0; p < 4; ++p)
        gl_lds16(gsrc[p] + ko, (p < 2 ? &As[nxt][lofs[p]] : &Bs[nxt][lofs[p]]));
    }
    half8 af[4], bf[4];
#pragma unroll
    for (int i = 0; i < 4; ++i)
      af[i] = *reinterpret_cast<const half8*>(&As[cur][((hh * 4 + i) * 4 + quad) * 128 + l16 * 8]);
#pragma unroll
    for (int n = 0; n < 4; ++n)
      bf[n] = *reinterpret_cast<const half8*>(&Bs[cur][((gg * 4 + n) * 4 + quad) * 128 + l16 * 8]);
#pragma unroll
    for (int i = 0; i < 4; ++i)
#pragma unroll
      for (int n = 0; n < 4; ++n)
        acc[i][n] = __builtin_amdgcn_mfma_f32_16x16x32_f16(af[i], bf[n], acc[i][n], 0, 0, 0);
  }

  const int wm = hh * 64, wn = gg * 64;
#pragma unroll
  for (int n = 0; n < 4; ++n) {
    const int gc = bn + wn + n * 16 + l16;
    const float* bp = (gc < 2048) ? b0 : (gc < 4096 ? b1 : b2);
    const float bz = bp[gc & 2047];
#pragma unroll
    for (int i = 0; i < 4; ++i) {
#pragma unroll
      for (int r = 0; r < 4; ++r) {
        const int gr = bm + wm + i * 16 + quad * 4 + r;
        float v = acc[i][n][r] + bz;
        if (OUT_F32)
          reinterpret_cast<float*>(Cout)[(size_t)gr * N + gc] = v;
        else
          reinterpret_cast<_Float16*>(Cout)[(size_t)gr * N + gc] = (_Float16)v;
      }
    }
  }
}

// ---------------- RoPE in-place on fused qkv (rows stride 6144) ----------------
// Also folds the softmax scale 1/sqrt(dh) into q.
__global__ void rope_inplace(_Float16* __restrict__ qkv, int ngroups) {
  int idx = blockIdx.x * blockDim.x + threadIdx.x;
  if (idx >= ngroups) return;
  int m = idx >> 8;        // row in (B*S); 256 groups of 4 pairs per row
  int g = idx & 255;
  int s = m & 2047;
  const float scale = 0.088388347648318447f;  // 1/sqrt(128)
  size_t base = (size_t)m * 6144 + g * 8;
  half8 qv = *reinterpret_cast<const half8*>(qkv + base);
  half8 kv = *reinterpret_cast<const half8*>(qkv + base + 2048);
  half8 qo, ko;
#pragma unroll
  for (int j = 0; j < 4; ++j) {
    int i = (g * 4 + j) & 63;  // freq index within head (dh/2 = 64)
    float ang = (float)s * exp2f(-0.2076205059304601f * (float)i);
    float sn, cs;
    __sincosf(ang, &sn, &cs);
    float e = (float)qv[j * 2], o = (float)qv[j * 2 + 1];
    qo[j * 2]     = (_Float16)((e * cs - o * sn) * scale);
    qo[j * 2 + 1] = (_Float16)((o * cs + e * sn) * scale);
    e = (float)kv[j * 2]; o = (float)kv[j * 2 + 1];
    ko[j * 2]     = (_Float16)(e * cs - o * sn);
    ko[j * 2 + 1] = (_Float16)(o * cs + e * sn);
  }
  *reinterpret_cast<half8*>(qkv + base) = qo;
  *reinterpret_cast<half8*>(qkv + base + 2048) = ko;
}

// ---------------- V transpose: qkv v-cols (stride 6144) -> (B,H,dh,S) ----------------
__global__ __launch_bounds__(256) void transpose_v(const _Float16* __restrict__ qkv,
                                                   _Float16* __restrict__ vt) {
  __shared__ _Float16 t[64][72];
  const int s0 = blockIdx.x * 64;
  const int d0 = blockIdx.y * 64;
  const int bh = blockIdx.z;
  const int b = bh >> 4, h = bh & 15;
  const int tid = threadIdx.x;
#pragma unroll
  for (int p = 0; p < 2; ++p) {
    int chunk = p * 256 + tid;
    int r = chunk >> 3, c8 = (chunk & 7) * 8;
    *reinterpret_cast<half8*>(&t[r][c8]) = *reinterpret_cast<const half8*>(
        &qkv[(size_t)(b * 2048 + s0 + r) * 6144 + 4096 + h * 128 + d0 + c8]);
  }
  __syncthreads();
#pragma unroll
  for (int p = 0; p < 2; ++p) {
    int chunk = p * 256 + tid;
    int dr = chunk >> 3, c8 = (chunk & 7) * 8;
    half8 o;
#pragma unroll
    for (int j = 0; j < 8; ++j) o[j] = t[c8 + j][dr];
    *reinterpret_cast<half8*>(&vt[(size_t)(bh * 128 + d0 + dr) * 2048 + s0 + c8]) = o;
  }
}

// ---------------- Flash attention (causal), dbuf LDS K/V ----------------
// 1D grid, heavy-first: bh = bid&31 (fastest), qt = 31 - (bid>>5).
// Block: 64 Q-rows, 4 waves x 16 rows. 64-key tiles, K/V double-buffered:
// barrier -> issue next-tile global_load_lds -> compute current -> loop.
// Row-sums (l_i) accumulate via MFMA with a ones B-operand.
__global__ __launch_bounds__(256, 2) void attn_kernel(
    const _Float16* __restrict__ QKV,  // (4096, 6144): q|k|v
    const _Float16* __restrict__ VT,   // (32, 128, 2048)
    _Float16* __restrict__ ctx) {      // (4096, 2048)
  constexpr int LD = 6144, S = 2048;
  __shared__ _Float16 Ks[2][8192];   // 32 KB
  __shared__ _Float16 Vs[2][8192];   // 32 KB
  __shared__ _Float16 P[4][16][80];  // 10 KB (stride 80: conflict-free b128 reads)
  const int bid = blockIdx.x;
  const int bh = bid & 31;
  const int qt = 31 - (bid >> 5);
  const int b = bh >> 4, h = bh & 15;
  const int tid = threadIdx.x;
  const int wv = tid >> 6, lane = tid & 63;
  const int quad = lane >> 4, l16 = lane & 15;
  const int q0 = qt * 64 + wv * 16;

  // Q fragments (q pre-scaled by 1/sqrt(dh) in rope), kept in regs
  const _Float16* qp = QKV + (size_t)(b * S + q0 + l16) * LD + h * 128;
  half8 aq[4];
#pragma unroll
  for (int ks = 0; ks < 4; ++ks)
    aq[ks] = *reinterpret_cast<const half8*>(qp + ks * 32 + quad * 8);

  // staging addresses (K: rows=keys stride LD; V: rows=dh stride S)
  const _Float16* gk[4];
  const _Float16* gv[4];
  int lofs[4];
#pragma unroll
  for (int p = 0; p < 4; ++p) {
    int c = p * 256 + tid;  // [0,1024)
    int cl16 = c & 15, cqd = (c >> 4) & 3;
    int cks = (c >> 6) & 3, cf = c >> 8;
    gk[p] = QKV + (size_t)(b * S + cf * 16 + cl16) * LD + 2048 + h * 128 + cks * 32 + cqd * 8;
    int ckv = (c >> 6) & 1, ct = c >> 7;
    gv[p] = VT + (size_t)(bh * 128 + ct * 16 + cl16) * S + ckv * 32 + cqd * 8;
    lofs[p] = c * 8;
  }

  f32x4 acc[8];
#pragma unroll
  for (int t = 0; t < 8; ++t) acc[t] = f32x4{0.f, 0.f, 0.f, 0.f};
  f32x4 lacc = f32x4{0.f, 0.f, 0.f, 0.f};
  float m_i[4];
#pragma unroll
  for (int r = 0; r < 4; ++r) m_i[r] = -INFINITY;

  half8 ones;
#pragma unroll
  for (int j = 0; j < 8; ++j) ones[j] = (_Float16)1.0f;

  // prologue: stage tile 0 into buf 0
#pragma unroll
  for (int p = 0; p < 4; ++p) gl_lds16(gk[p], &Ks[0][lofs[p]]);
#pragma unroll
  for (int p = 0; p < 4; ++p) gl_lds16(gv[p], &Vs[0][lofs[p]]);

  for (int j = 0; j <= qt; ++j) {
    __syncthreads();  // buf[j&1] staged; prior tile's reads complete
    const int cur = j & 1;
    if (j < qt) {
      const size_t ko = (size_t)(j + 1) * 64 * LD;
      const int vo = (j + 1) * 64;
#pragma unroll
      for (int p = 0; p < 4; ++p) gl_lds16(gk[p] + ko, &Ks[cur ^ 1][lofs[p]]);
#pragma unroll
      for (int p = 0; p < 4; ++p) gl_lds16(gv[p] + vo, &Vs[cur ^ 1][lofs[p]]);
    }
    // ---- QK^T: 16 rows x 64 keys ----
    f32x4 sf[4];
#pragma unroll
    for (int f = 0; f < 4; ++f) sf[f] = f32x4{0.f, 0.f, 0.f, 0.f};
#pragma unroll
    for (int f = 0; f < 4; ++f)
#pragma unroll
      for (int ks = 0; ks < 4; ++ks) {
        half8 bk = *reinterpret_cast<const half8*>(&Ks[cur][((f * 4 + ks) * 4 + quad) * 128 + l16 * 8]);
        sf[f] = __builtin_amdgcn_mfma_f32_16x16x32_f16(aq[ks], bk, sf[f], 0, 0, 0);
      }
    // ---- causal mask: diagonal tile only ----
    if (j == qt) {
      const int key0 = j * 64;
#pragma unroll
      for (int f = 0; f < 4; ++f) {
        const int key = key0 + f * 16 + l16;
#pragma unroll
        for (int r = 0; r < 4; ++r) {
          const int row = q0 + quad * 4 + r;
          sf[f][r] = (key <= row) ? sf[f][r] : -1e30f;
        }
      }
    }
    // ---- online softmax (max via shfl; sum via MFMA below) ----
    float alpha[4];
#pragma unroll
    for (int r = 0; r < 4; ++r) {
      float tm = fmaxf(fmaxf(sf[0][r], sf[1][r]), fmaxf(sf[2][r], sf[3][r]));
      tm = fmaxf(tm, __shfl_xor(tm, 1));
      tm = fmaxf(tm, __shfl_xor(tm, 2));
      tm = fmaxf(tm, __shfl_xor(tm, 4));
      tm = fmaxf(tm, __shfl_xor(tm, 8));
      const float mn = fmaxf(m_i[r], tm);
      alpha[r] = __expf(m_i[r] - mn);
      m_i[r] = mn;
    }
    // ---- exp -> P (fp16, C->A layout via per-wave LDS) ----
#pragma unroll
    for (int f = 0; f < 4; ++f)
#pragma unroll
      for (int r = 0; r < 4; ++r)
        P[wv][quad * 4 + r][f * 16 + l16] = (_Float16)__expf(sf[f][r] - m_i[r]);
    half8 pa0 = *reinterpret_cast<const half8*>(&P[wv][l16][quad * 8]);
    half8 pa1 = *reinterpret_cast<const half8*>(&P[wv][l16][32 + quad * 8]);
    // ---- rescale accumulators, then PV + l-sum MFMA ----
#pragma unroll
    for (int t = 0; t < 8; ++t)
#pragma unroll
      for (int r = 0; r < 4; ++r) acc[t][r] *= alpha[r];
#pragma unroll
    for (int r = 0; r < 4; ++r) lacc[r] *= alpha[r];
#pragma unroll
    for (int t = 0; t < 8; ++t) {
      half8 bv0 = *reinterpret_cast<const half8*>(&Vs[cur][((t * 2 + 0) * 4 + quad) * 128 + l16 * 8]);
      half8 bv1 = *reinterpret_cast<const half8*>(&Vs[cur][((t * 2 + 1) * 4 + quad) * 128 + l16 * 8]);
      acc[t] = __builtin_amdgcn_mfma_f32_16x16x32_f16(pa0, bv0, acc[t], 0, 0, 0);
      acc[t] = __builtin_amdgcn_mfma_f32_16x16x32_f16(pa1, bv1, acc[t], 0, 0, 0);
    }
    lacc = __builtin_amdgcn_mfma_f32_16x16x32_f16(pa0, ones, lacc, 0, 0, 0);
    lacc = __builtin_amdgcn_mfma_f32_16x16x32_f16(pa1, ones, lacc, 0, 0, 0);
  }

  // ---- epilogue ----
  float inv[4];
#pragma unroll
  for (int r = 0; r < 4; ++r) inv[r] = 1.0f / lacc[r];
#pragma unroll
  for (int t = 0; t < 8; ++t)
#pragma unroll
    for (int r = 0; r < 4; ++r)
      ctx[(size_t)(b * S + q0 + quad * 4 + r) * 2048 + h * 128 + t * 16 + l16] =
          (_Float16)(acc[t][r] * inv[r]);
}

// ---------------- launcher ----------------
extern "C" void kernel_launch(void* const* d_in, const int* in_sizes, int n_in,
                              void* d_out, int out_size, void* d_ws, size_t ws_size,
                              hipStream_t stream) {
  const float* x  = (const float*)d_in[0];
  const float* wq = (const float*)d_in[1];
  const float* bq = (const float*)d_in[2];
  const float* wk = (const float*)d_in[3];
  const float* bk = (const float*)d_in[4];
  const float* wv = (const float*)d_in[5];
  const float* bv = (const float*)d_in[6];
  const float* wo = (const float*)d_in[7];
  const float* bo = (const float*)d_in[8];
  // d_in[9] = mask: causal triu(k=1), hardcoded in attn_kernel.

  // workspace (fp16 elems), 96 MB total
  _Float16* W      = (_Float16*)d_ws;
  _Float16* xh     = W;                  // 16 MB (4096,2048)
  _Float16* wqkvh  = xh + 8388608;       // 24 MB (6144,2048) contiguous wq|wk|wv
  _Float16* woh    = wqkvh + 12582912;   // 8 MB  (2048,2048)
  _Float16* qkvlin = woh + 4194304;      // 48 MB (4096,6144)
  _Float16* vT     = xh;                 // reuse: x dead after QKV gemm
  _Float16* ctx    = wqkvh;              // reuse: wqkv dead after QKV gemm (16 MB)

  cast_f32_f16<<<8192, 256, 0, stream>>>(x, xh, 2097152);
  cast_w<<<dim3(4096, 4), 256, 0, stream>>>(wq, wk, wv, wo, wqkvh);

  // fused QKV gemm: (4096,2048) x (6144,2048)^T -> (4096,6144)
  gemm_bt<false><<<dim3(48, 32), 256, 0, stream>>>(xh, wqkvh, bq, bk, bv, qkvlin,
                                                   4096, 6144, 2048);

  rope_inplace<<<4096, 256, 0, stream>>>(qkvlin, 1048576);
  transpose_v<<<dim3(32, 2, 32), 256, 0, stream>>>(qkvlin, vT);
  attn_kernel<<<1024, 256, 0, stream>>>(qkvlin, vT, ctx);

  // output gemm: (4096,2048) x (2048,2048)^T -> fp32 out
  gemm_bt<true><<<dim3(16, 32), 256, 0, stream>>>(ctx, woh, bo, bo, bo, (float*)d_out,
                                                  4096, 2048, 2048);
}